// Round 15
// baseline (737.253 us; speedup 1.0000x reference)
//
#include <hip/hip_runtime.h>

// RNN: h_{t+1} = tanh(W h_t + w_bias + V x_t + v_bias)
// x: [S,B,I] f32; out = h_seq [S,B,H] f32 ++ h_final [B,H] f32.
// S=2048 B=2048 I=16 H=64.
//
// R15: 2 batch-tiles per block, interleaved in the same waves. R12-R14 fit:
// ~41 cyc/tanh + O~380 cyc/step fixed overhead (barrier + exch ds_read
// latency + MFMA dep). Tanh-splitting is exhausted (4 producers on 4 SIMDs'
// trans units); O is pure latency -> fill it with an INDEPENDENT second
// recurrence. Weights are batch-independent (shared registers). Per
// producer step: 8 exch b64 reads, 6 MFMA (2 interleaved chains), 8 tanh,
// 2 quad writes; one barrier for both tiles. Latency amortizes across
// tiles; issue adds. Contraction order per tile unchanged -> absmax must
// stay bit-exact 0.01074219.
// Waves: 4 producers (chain m, both tiles), 2 consumers (quads 2cw,2cw+1,
// both tiles), 1 stager (both tiles). Grid = B/32 = 64 blocks.

typedef short short8v __attribute__((ext_vector_type(8)));
typedef float f32x4   __attribute__((ext_vector_type(4)));

constexpr int S = 2048, B = 2048, I = 16, H = 64;
constexpr int RB = 16;    // rows per tile
constexpr int XR = 24;    // ushorts per x row: 16 data + 8 zero pad
constexpr int NT = 448;   // 7 waves

static __device__ __forceinline__ unsigned short f2bf(float f) {
    unsigned u = __builtin_bit_cast(unsigned, f);
    return (unsigned short)((u + 0x7FFFu + ((u >> 16) & 1u)) >> 16);
}
static __device__ __forceinline__ unsigned cvtpk(float lo, float hi) {
    unsigned r;
    asm("v_cvt_pk_bf16_f32 %0, %1, %2" : "=v"(r) : "v"(lo), "v"(hi));
    return r;
}
static __device__ __forceinline__ float tanh_fast(float p) {
    float e = __builtin_amdgcn_exp2f(p * 2.8853900817779268f);
    return fmaf(-2.0f, __builtin_amdgcn_rcpf(e + 1.0f), 1.0f);
}
static __device__ __forceinline__ float bflo(unsigned d) {
    return __builtin_bit_cast(float, d << 16);
}
static __device__ __forceinline__ float bfhi(unsigned d) {
    return __builtin_bit_cast(float, d & 0xFFFF0000u);
}

#define MFMA(A, Bf, C) __builtin_amdgcn_mfma_f32_16x16x32_bf16((A), (Bf), (C), 0, 0, 0)
#define LDS_BARRIER()                                         \
    do {                                                      \
        asm volatile("s_waitcnt lgkmcnt(0)" ::: "memory");    \
        __builtin_amdgcn_s_barrier();                         \
        asm volatile("" ::: "memory");                        \
    } while (0)

__global__ __launch_bounds__(NT)
__attribute__((amdgpu_waves_per_eu(1)))
void rnn_2tile(const float* __restrict__ x,
               const float* __restrict__ Wm,
               const float* __restrict__ wb,
               const float* __restrict__ Vm,
               const float* __restrict__ vb,
               float* __restrict__ out)
{
    const int tid = threadIdx.x;
    const int wv  = tid >> 6;          // 0-3 producers, 4-5 consumers, 6 stager
    const int l   = tid & 63;
    const int c   = l & 15;            // batch-in-tile
    const int g   = l >> 4;            // k-group
    const int bB  = blockIdx.x * 2 * RB;   // block batch base (32 rows)

    // xs[buf][step][tile][row][XR]; exch[buf][tile][quad][lane]
    __shared__ __align__(16) unsigned short xs[2][8][2][RB][XR];  // 24 KB
    __shared__ __align__(8)  uint2 exch[2][2][4][64];             // 8 KB

    // zero xs (incl. pad) and exch (h_0 = 0)
    for (int q = tid; q < (int)(sizeof(xs) / 4); q += NT)
        ((unsigned*)&xs[0][0][0][0][0])[q] = 0u;
    for (int q = tid; q < (int)(sizeof(exch) / 4); q += NT)
        ((unsigned*)&exch[0][0][0][0])[q] = 0u;
    // stage x chunk 0: 1024 float4
    for (int q = tid; q < 1024; q += NT) {
        int i4 = q & 3, cc = (q >> 2) & 15, tl = (q >> 6) & 1, tc = q >> 7;
        float4 t4 = *(const float4*)(x + ((size_t)tc * B + bB + tl * RB + cc) * I + 4 * i4);
        uint2 p;
        p.x = cvtpk(t4.x, t4.y);
        p.y = cvtpk(t4.z, t4.w);
        *(uint2*)(&xs[0][tc][tl][cc][4 * i4]) = p;
    }
    __syncthreads();

    if (wv < 4) {
        // ============ PRODUCER: chain m = wv, tiles 0 and 1 ============
        const int m = wv;
        short8v Wlo, Whi, VA;     // shared across tiles (batch-independent)
        f32x4 bs;
        {
            const int o = 32 * (m >> 1) + 8 * (c >> 2) + 4 * (m & 1) + (c & 3);
            const float* wr = Wm + o * H + 8 * g;
#pragma unroll
            for (int j = 0; j < 8; ++j) {
                Wlo[j] = (short)f2bf(wr[j]);
                Whi[j] = (short)f2bf(wr[32 + j]);
            }
            const float* vr = Vm + o * I;
#pragma unroll
            for (int j = 0; j < 8; ++j) {
                int k = 8 * g + j;
                VA[j] = (k < I) ? (short)f2bf(vr[k]) : (short)0;
            }
            const int ob = 32 * (m >> 1) + 8 * g + 4 * (m & 1);
            bs[0] = wb[ob] + vb[ob];
            bs[1] = wb[ob + 1] + vb[ob + 1];
            bs[2] = wb[ob + 2] + vb[ob + 2];
            bs[3] = wb[ob + 3] + vb[ob + 3];
        }
        const int xi = (g < 2) ? 8 * g : 16;

        for (int chunk = 0; chunk < S / 8; ++chunk) {
#pragma unroll
            for (int half = 0; half < 2; ++half) {
                // burst-read 4 steps x 2 tiles of BX (32 VGPR)
                const unsigned short* xb =
                    &xs[chunk & 1][half * 4][0][c][xi];
                const int SSTEP = 2 * RB * XR;   // step stride (ushorts)
                short8v BXa0 = *(const short8v*)(xb + 0 * SSTEP);
                short8v BXb0 = *(const short8v*)(xb + 0 * SSTEP + RB * XR);
                short8v BXa1 = *(const short8v*)(xb + 1 * SSTEP);
                short8v BXb1 = *(const short8v*)(xb + 1 * SSTEP + RB * XR);
                short8v BXa2 = *(const short8v*)(xb + 2 * SSTEP);
                short8v BXb2 = *(const short8v*)(xb + 2 * SSTEP + RB * XR);
                short8v BXa3 = *(const short8v*)(xb + 3 * SSTEP);
                short8v BXb3 = *(const short8v*)(xb + 3 * SSTEP + RB * XR);

#define STEP(tq, BXa, BXb)                                                    \
                {                                                             \
                    const int t = chunk * 8 + half * 4 + (tq);                \
                    uint2 qa0 = exch[t & 1][0][0][l];                         \
                    uint2 qa1 = exch[t & 1][0][1][l];                         \
                    uint2 qa2 = exch[t & 1][0][2][l];                         \
                    uint2 qa3 = exch[t & 1][0][3][l];                         \
                    uint2 qb0 = exch[t & 1][1][0][l];                         \
                    uint2 qb1 = exch[t & 1][1][1][l];                         \
                    uint2 qb2 = exch[t & 1][1][2][l];                         \
                    uint2 qb3 = exch[t & 1][1][3][l];                         \
                    uint4 v0a; v0a.x = qa0.x; v0a.y = qa0.y; v0a.z = qa1.x; v0a.w = qa1.y; \
                    uint4 v1a; v1a.x = qa2.x; v1a.y = qa2.y; v1a.z = qa3.x; v1a.w = qa3.y; \
                    uint4 v0b; v0b.x = qb0.x; v0b.y = qb0.y; v0b.z = qb1.x; v0b.w = qb1.y; \
                    uint4 v1b; v1b.x = qb2.x; v1b.y = qb2.y; v1b.z = qb3.x; v1b.w = qb3.y; \
                    short8v B0a = __builtin_bit_cast(short8v, v0a);           \
                    short8v B1a = __builtin_bit_cast(short8v, v1a);           \
                    short8v B0b = __builtin_bit_cast(short8v, v0b);           \
                    short8v B1b = __builtin_bit_cast(short8v, v1b);           \
                    f32x4 aa = bs, ab = bs;                                   \
                    aa = MFMA(VA, BXa, aa);  ab = MFMA(VA, BXb, ab);          \
                    aa = MFMA(Wlo, B0a, aa); ab = MFMA(Wlo, B0b, ab);         \
                    aa = MFMA(Whi, B1a, aa); ab = MFMA(Whi, B1b, ab);         \
                    float ha0 = tanh_fast(aa[0]), ha1 = tanh_fast(aa[1]);     \
                    float ha2 = tanh_fast(aa[2]), ha3 = tanh_fast(aa[3]);     \
                    float hb0 = tanh_fast(ab[0]), hb1 = tanh_fast(ab[1]);     \
                    float hb2 = tanh_fast(ab[2]), hb3 = tanh_fast(ab[3]);     \
                    uint2 na, nb;                                             \
                    na.x = cvtpk(ha0, ha1); na.y = cvtpk(ha2, ha3);           \
                    nb.x = cvtpk(hb0, hb1); nb.y = cvtpk(hb2, hb3);           \
                    exch[(t + 1) & 1][0][m][l] = na;                          \
                    exch[(t + 1) & 1][1][m][l] = nb;                          \
                    LDS_BARRIER();                                            \
                }
                STEP(0, BXa0, BXb0)
                STEP(1, BXa1, BXb1)
                STEP(2, BXa2, BXb2)
                STEP(3, BXa3, BXb3)
#undef STEP
            }
        }
    } else if (wv < 6) {
        // ========= CONSUMER cw: quads 2cw,2cw+1, both tiles =========
        const int cw   = wv - 4;
        const int offq = 32 * cw;
        for (int t = 0; t < S; ++t) {
            if (t >= 1) {
#pragma unroll
                for (int tl = 0; tl < 2; ++tl) {
                    uint2 ra = exch[t & 1][tl][2 * cw][l];
                    uint2 rb = exch[t & 1][tl][2 * cw + 1][l];
                    float4 ha, hb;
                    ha.x = bflo(ra.x); ha.y = bfhi(ra.x);
                    ha.z = bflo(ra.y); ha.w = bfhi(ra.y);
                    hb.x = bflo(rb.x); hb.y = bfhi(rb.x);
                    hb.z = bflo(rb.y); hb.w = bfhi(rb.y);
                    float* op = out + ((size_t)(t - 1) * B + bB + tl * RB + c) * H + 8 * g + offq;
                    *(float4*)(op + 0) = ha;
                    *(float4*)(op + 4) = hb;
                }
            }
            LDS_BARRIER();
        }
#pragma unroll
        for (int tl = 0; tl < 2; ++tl) {   // h_seq[S-1] + h_final
            uint2 ra = exch[0][tl][2 * cw][l];
            uint2 rb = exch[0][tl][2 * cw + 1][l];
            float4 ha, hb;
            ha.x = bflo(ra.x); ha.y = bfhi(ra.x);
            ha.z = bflo(ra.y); ha.w = bfhi(ra.y);
            hb.x = bflo(rb.x); hb.y = bfhi(rb.x);
            hb.z = bflo(rb.y); hb.w = bfhi(rb.y);
            float* op = out + ((size_t)(S - 1) * B + bB + tl * RB + c) * H + 8 * g + offq;
            *(float4*)(op + 0) = ha;
            *(float4*)(op + 4) = hb;
            float* fp = out + (size_t)S * B * H + (size_t)(bB + tl * RB + c) * H + 8 * g + offq;
            *(float4*)(fp + 0) = ha;
            *(float4*)(fp + 4) = hb;
        }
    } else {
        // ===================== STAGER (both tiles) =====================
        float4 d00, d01, d02, d03, d04, d05, d06, d07;
        float4 d08, d09, d10, d11, d12, d13, d14, d15;
        for (int t = 0; t < S; ++t) {
            const int k = t >> 3;
            if ((t & 7) == 0 && k + 1 < S / 8) {
                const float* xb = x + (size_t)(k + 1) * 8 * B * I;
#define LD(m2, dst)                                                        \
                {                                                          \
                    int q = l + 64 * (m2);                                 \
                    int i4 = q & 3, cc = (q >> 2) & 15;                    \
                    int tl = (q >> 6) & 1, tc = q >> 7;                    \
                    dst = *(const float4*)(xb + ((size_t)tc * B + bB + tl * RB + cc) * I + 4 * i4); \
                }
                LD(0, d00)  LD(1, d01)  LD(2, d02)  LD(3, d03)
                LD(4, d04)  LD(5, d05)  LD(6, d06)  LD(7, d07)
                LD(8, d08)  LD(9, d09)  LD(10, d10) LD(11, d11)
                LD(12, d12) LD(13, d13) LD(14, d14) LD(15, d15)
#undef LD
            }
            if ((t & 7) == 4 && k + 1 < S / 8) {
                asm volatile("s_waitcnt vmcnt(0)" ::: "memory");
                const int buf = (k + 1) & 1;
#define WR(m2, src)                                                        \
                {                                                          \
                    int q = l + 64 * (m2);                                 \
                    int i4 = q & 3, cc = (q >> 2) & 15;                    \
                    int tl = (q >> 6) & 1, tc = q >> 7;                    \
                    uint2 p;                                               \
                    p.x = cvtpk(src.x, src.y);                             \
                    p.y = cvtpk(src.z, src.w);                             \
                    *(uint2*)(&xs[buf][tc][tl][cc][4 * i4]) = p;           \
                }
                WR(0, d00)  WR(1, d01)  WR(2, d02)  WR(3, d03)
                WR(4, d04)  WR(5, d05)  WR(6, d06)  WR(7, d07)
                WR(8, d08)  WR(9, d09)  WR(10, d10) WR(11, d11)
                WR(12, d12) WR(13, d13) WR(14, d14) WR(15, d15)
#undef WR
            }
            LDS_BARRIER();
        }
    }
}

extern "C" void kernel_launch(void* const* d_in, const int* in_sizes, int n_in,
                              void* d_out, int out_size, void* d_ws, size_t ws_size,
                              hipStream_t stream) {
    const float* x  = (const float*)d_in[0];
    const float* Wm = (const float*)d_in[1];
    const float* wb = (const float*)d_in[2];
    const float* Vm = (const float*)d_in[3];
    const float* vb = (const float*)d_in[4];
    float* out = (float*)d_out;

    rnn_2tile<<<B / (2 * RB), NT, 0, stream>>>(x, Wm, wb, Vm, vb, out);
}

// Round 16
// 551.477 us; speedup vs baseline: 1.3369x; 1.3369x over previous
//
#include <hip/hip_runtime.h>

// RNN: h_{t+1} = tanh(W h_t + w_bias + V x_t + v_bias)
// x: [S,B,I] f32; out = h_seq [S,B,H] f32 ++ h_final [B,H] f32.
// S=2048 B=2048 I=16 H=64.
//
// R16: R14 structure (464us, validated) + rational tanh. R15 (2-tile) was a
// modeling error: wall = S x cyc/step regardless of tiles/block (blocks are
// abundant); packing tiles adds issue to the same serial wave. Reverted.
// R12-R14 fit: cyc/step = 41*tanh_per_wave + O(380). 4 producers already
// saturate all 4 trans units/CU, so the lever is trans occupancy per tanh:
// exp+rcp = 2 trans (32 cyc) -> Eigen rational 13/4 (1 rcp + ~13 VALU,
// ~1 ulp f32). Trans/wave/step: 128 -> 64 cyc; VALU issues in parallel.
// ONLY tanh_fast changes vs R14.

typedef short short8v __attribute__((ext_vector_type(8)));
typedef float f32x4   __attribute__((ext_vector_type(4)));

constexpr int S = 2048, B = 2048, I = 16, H = 64;
constexpr int RB = 16;    // batch rows per block
constexpr int XR = 24;    // ushorts per x row: 16 data + 8 zero pad
constexpr int NT = 448;   // 7 waves

static __device__ __forceinline__ unsigned short f2bf(float f) {
    unsigned u = __builtin_bit_cast(unsigned, f);
    return (unsigned short)((u + 0x7FFFu + ((u >> 16) & 1u)) >> 16);
}
static __device__ __forceinline__ unsigned cvtpk(float lo, float hi) {
    unsigned r;
    asm("v_cvt_pk_bf16_f32 %0, %1, %2" : "=v"(r) : "v"(lo), "v"(hi));
    return r;
}
// Eigen ptanh<float> rational 13/4: 1 trans (rcp) + ~13 VALU, ~1 ulp.
static __device__ __forceinline__ float tanh_fast(float x) {
    const float L = 7.90531110763549805f;
    float xc = fminf(fmaxf(x, -L), L);
    float s  = xc * xc;
    float p  = -2.76076847742355e-16f;
    p = fmaf(s, p,  2.00018790482477e-13f);
    p = fmaf(s, p, -8.60467152213735e-11f);
    p = fmaf(s, p,  5.12229709037114e-08f);
    p = fmaf(s, p,  1.48572235717979e-05f);
    p = fmaf(s, p,  6.37261928875436e-04f);
    p = fmaf(s, p,  4.89352455891786e-03f);
    p = xc * p;
    float q = 1.19825839466702e-06f;
    q = fmaf(s, q,  1.18534705686654e-04f);
    q = fmaf(s, q,  2.26843463243900e-03f);
    q = fmaf(s, q,  4.89352518554385e-03f);
    return p * __builtin_amdgcn_rcpf(q);
}
static __device__ __forceinline__ float bflo(unsigned d) {
    return __builtin_bit_cast(float, d << 16);
}
static __device__ __forceinline__ float bfhi(unsigned d) {
    return __builtin_bit_cast(float, d & 0xFFFF0000u);
}

#define MFMA(A, Bf, C) __builtin_amdgcn_mfma_f32_16x16x32_bf16((A), (Bf), (C), 0, 0, 0)
#define LDS_BARRIER()                                         \
    do {                                                      \
        asm volatile("s_waitcnt lgkmcnt(0)" ::: "memory");    \
        __builtin_amdgcn_s_barrier();                         \
        asm volatile("" ::: "memory");                        \
    } while (0)

__global__ __launch_bounds__(NT)
__attribute__((amdgpu_waves_per_eu(1, 2)))
void rnn_split4(const float* __restrict__ x,
                const float* __restrict__ Wm,
                const float* __restrict__ wb,
                const float* __restrict__ Vm,
                const float* __restrict__ vb,
                float* __restrict__ out)
{
    const int tid = threadIdx.x;
    const int wv  = tid >> 6;          // 0-3 producers, 4-5 consumers, 6 stager
    const int l   = tid & 63;
    const int c   = l & 15;            // batch-in-tile
    const int g   = l >> 4;            // k-group
    const int b0  = blockIdx.x * RB;

    __shared__ __align__(16) unsigned short xs[2][8][RB][XR];  // 12 KB
    __shared__ __align__(8)  uint2 exch[2][4][64];             // 4 KB

    // zero xs (incl. pad) and exch (h_0 = 0)
    for (int q = tid; q < 2 * 8 * RB * XR / 2; q += NT)
        ((unsigned*)&xs[0][0][0][0])[q] = 0u;
    for (int q = tid; q < 2 * 4 * 64 * 2; q += NT)
        ((unsigned*)&exch[0][0][0])[q] = 0u;
    // stage x chunk 0 (512 float4)
    for (int q = tid; q < 512; q += NT) {
        int i4 = q & 3, cc = (q >> 2) & 15, tc = q >> 6;
        float4 t4 = *(const float4*)(x + ((size_t)tc * B + b0 + cc) * I + 4 * i4);
        uint2 p;
        p.x = cvtpk(t4.x, t4.y);
        p.y = cvtpk(t4.z, t4.w);
        *(uint2*)(&xs[0][tc][cc][4 * i4]) = p;
    }
    __syncthreads();

    if (wv < 4) {
        // ===================== PRODUCER, chain m = wv =====================
        const int m = wv;
        short8v Wlo, Whi, VA;
        f32x4 bs;
        {
            const int o = 32 * (m >> 1) + 8 * (c >> 2) + 4 * (m & 1) + (c & 3);
            const float* wr = Wm + o * H + 8 * g;
#pragma unroll
            for (int j = 0; j < 8; ++j) {
                Wlo[j] = (short)f2bf(wr[j]);
                Whi[j] = (short)f2bf(wr[32 + j]);
            }
            const float* vr = Vm + o * I;
#pragma unroll
            for (int j = 0; j < 8; ++j) {
                int k = 8 * g + j;
                VA[j] = (k < I) ? (short)f2bf(vr[k]) : (short)0;
            }
            const int ob = 32 * (m >> 1) + 8 * g + 4 * (m & 1);
            bs[0] = wb[ob] + vb[ob];
            bs[1] = wb[ob + 1] + vb[ob + 1];
            bs[2] = wb[ob + 2] + vb[ob + 2];
            bs[3] = wb[ob + 3] + vb[ob + 3];
        }
        const int xi = (g < 2) ? 8 * g : 16;

        for (int chunk = 0; chunk < S / 8; ++chunk) {
            // burst-read the chunk's 8 x-fragments into registers
            const unsigned short* xb = &xs[chunk & 1][0][c][xi];
            short8v BX0 = *(const short8v*)(xb + 0 * RB * XR);
            short8v BX1 = *(const short8v*)(xb + 1 * RB * XR);
            short8v BX2 = *(const short8v*)(xb + 2 * RB * XR);
            short8v BX3 = *(const short8v*)(xb + 3 * RB * XR);
            short8v BX4 = *(const short8v*)(xb + 4 * RB * XR);
            short8v BX5 = *(const short8v*)(xb + 5 * RB * XR);
            short8v BX6 = *(const short8v*)(xb + 6 * RB * XR);
            short8v BX7 = *(const short8v*)(xb + 7 * RB * XR);

#define STEP(tq, BXs)                                                         \
            {                                                                 \
                const int t = chunk * 8 + (tq);                               \
                uint2 q0 = exch[t & 1][0][l];                                 \
                uint2 q1 = exch[t & 1][1][l];                                 \
                uint2 q2 = exch[t & 1][2][l];                                 \
                uint2 q3 = exch[t & 1][3][l];                                 \
                uint4 b0v; b0v.x = q0.x; b0v.y = q0.y; b0v.z = q1.x; b0v.w = q1.y; \
                uint4 b1v; b1v.x = q2.x; b1v.y = q2.y; b1v.z = q3.x; b1v.w = q3.y; \
                short8v B0h = __builtin_bit_cast(short8v, b0v);               \
                short8v B1h = __builtin_bit_cast(short8v, b1v);               \
                f32x4 a = bs;                                                 \
                a = MFMA(VA, BXs, a);   /* reg-only: hides exch latency */    \
                a = MFMA(Wlo, B0h, a);                                        \
                a = MFMA(Whi, B1h, a);                                        \
                float h0 = tanh_fast(a[0]), h1 = tanh_fast(a[1]);             \
                float h2 = tanh_fast(a[2]), h3 = tanh_fast(a[3]);             \
                uint2 nb;                                                     \
                nb.x = cvtpk(h0, h1);                                         \
                nb.y = cvtpk(h2, h3);                                         \
                exch[(t + 1) & 1][m][l] = nb;                                 \
                LDS_BARRIER();                                                \
            }
            STEP(0, BX0) STEP(1, BX1) STEP(2, BX2) STEP(3, BX3)
            STEP(4, BX4) STEP(5, BX5) STEP(6, BX6) STEP(7, BX7)
#undef STEP
        }
    } else if (wv < 6) {
        // ================= CONSUMER cw: quads 2cw, 2cw+1 =================
        const int cw   = wv - 4;
        const int offq = 32 * cw;          // float offset of chain 2cw
        for (int t = 0; t < S; ++t) {
            if (t >= 1) {
                uint2 ra = exch[t & 1][2 * cw][l];
                uint2 rb = exch[t & 1][2 * cw + 1][l];
                float4 ha, hb;
                ha.x = bflo(ra.x); ha.y = bfhi(ra.x);
                ha.z = bflo(ra.y); ha.w = bfhi(ra.y);
                hb.x = bflo(rb.x); hb.y = bfhi(rb.x);
                hb.z = bflo(rb.y); hb.w = bfhi(rb.y);
                float* op = out + ((size_t)(t - 1) * B + b0 + c) * H + 8 * g + offq;
                *(float4*)(op + 0) = ha;
                *(float4*)(op + 4) = hb;
            }
            LDS_BARRIER();
        }
        {   // h_seq[S-1] + h_final from exch[S&1] == exch[0]
            uint2 ra = exch[0][2 * cw][l];
            uint2 rb = exch[0][2 * cw + 1][l];
            float4 ha, hb;
            ha.x = bflo(ra.x); ha.y = bfhi(ra.x);
            ha.z = bflo(ra.y); ha.w = bfhi(ra.y);
            hb.x = bflo(rb.x); hb.y = bfhi(rb.x);
            hb.z = bflo(rb.y); hb.w = bfhi(rb.y);
            float* op = out + ((size_t)(S - 1) * B + b0 + c) * H + 8 * g + offq;
            *(float4*)(op + 0) = ha;
            *(float4*)(op + 4) = hb;
            float* fp = out + (size_t)S * B * H + (size_t)(b0 + c) * H + 8 * g + offq;
            *(float4*)(fp + 0) = ha;
            *(float4*)(fp + 4) = hb;
        }
    } else {
        // ============================ STAGER ============================
        float4 ld0, ld1, ld2, ld3, ld4, ld5, ld6, ld7;
        for (int t = 0; t < S; ++t) {
            const int k = t >> 3;
            if ((t & 7) == 0 && k + 1 < S / 8) {
                const float* xb = x + (size_t)(k + 1) * 8 * B * I;
#define LD(m2, dst)                                                        \
                {                                                          \
                    int q = l + 64 * (m2);                                 \
                    int i4 = q & 3, cc = (q >> 2) & 15, tc = q >> 6;       \
                    dst = *(const float4*)(xb + ((size_t)tc * B + b0 + cc) * I + 4 * i4); \
                }
                LD(0, ld0) LD(1, ld1) LD(2, ld2) LD(3, ld3)
                LD(4, ld4) LD(5, ld5) LD(6, ld6) LD(7, ld7)
#undef LD
            }
            if ((t & 7) == 4 && k + 1 < S / 8) {
                asm volatile("s_waitcnt vmcnt(0)" ::: "memory");
                const int buf = (k + 1) & 1;
#define WR(m2, src)                                                        \
                {                                                          \
                    int q = l + 64 * (m2);                                 \
                    int i4 = q & 3, cc = (q >> 2) & 15, tc = q >> 6;       \
                    uint2 p;                                               \
                    p.x = cvtpk(src.x, src.y);                             \
                    p.y = cvtpk(src.z, src.w);                             \
                    *(uint2*)(&xs[buf][tc][cc][4 * i4]) = p;               \
                }
                WR(0, ld0) WR(1, ld1) WR(2, ld2) WR(3, ld3)
                WR(4, ld4) WR(5, ld5) WR(6, ld6) WR(7, ld7)
#undef WR
            }
            LDS_BARRIER();
        }
    }
}

extern "C" void kernel_launch(void* const* d_in, const int* in_sizes, int n_in,
                              void* d_out, int out_size, void* d_ws, size_t ws_size,
                              hipStream_t stream) {
    const float* x  = (const float*)d_in[0];
    const float* Wm = (const float*)d_in[1];
    const float* wb = (const float*)d_in[2];
    const float* Vm = (const float*)d_in[3];
    const float* vb = (const float*)d_in[4];
    float* out = (float*)d_out;

    rnn_split4<<<B / RB, NT, 0, stream>>>(x, Wm, wb, Vm, vb, out);
}